// Round 7
// baseline (242.303 us; speedup 1.0000x reference)
//
#include <hip/hip_runtime.h>
#include <hip/hip_bf16.h>
#include <math.h>

#define EPSF 1e-15f

typedef __attribute__((ext_vector_type(8))) short bf16x8;
typedef __attribute__((ext_vector_type(16))) float f32x16;

__device__ __forceinline__ unsigned short f2bf(float x) {
    unsigned u = __float_as_uint(x);
    u += 0x7fffu + ((u >> 16) & 1u);
    return (unsigned short)(u >> 16);
}
__device__ __forceinline__ float bf2f(unsigned short b) {
    return __uint_as_float(((unsigned)b) << 16);
}
__device__ __forceinline__ unsigned pkbf(float lo, float hi) {
    __hip_bfloat162 h = __float22bfloat162_rn(make_float2(lo, hi));
    return *reinterpret_cast<unsigned*>(&h);
}
// tanh(x) for x>=0; identity form + small-x polynomial
__device__ __forceinline__ float fast_tanh_pos(float x) {
    if (x < 0.25f) { float x2 = x * x; return x * (1.0f - x2 * (0.33333334f - 0.13333334f * x2)); }
    float e = __expf(2.0f * x);
    return 1.0f - 2.0f / (e + 1.0f);
}
// atanh(y) for 0<=y<=1-1e-5
__device__ __forceinline__ float fast_atanh01(float y) {
    if (y < 0.125f) { float y2 = y * y; return y * (1.0f + y2 * (0.33333334f + 0.2f * y2)); }
    return 0.5f * __logf((1.0f + y) / (1.0f - y));
}

__device__ __forceinline__ float wred(float v) {
#pragma unroll
    for (int off = 32; off; off >>= 1) v += __shfl_xor(v, off);
    return v;
}

// ---------------------------------------------------------------------------
// prep: weight fragments for mfma_f32_32x32x16_bf16 (A-operand = weights).
// A layout: lane l holds A[row = l&31][k = 8*(l>>5)+i], i=0..7.
// fid 0..39: W1, fid = ks*2 + t (ks=0..19, t=out-tile): k natural:
//   val = W1[32t + (l&31)][16ks + 8*(l>>5) + i]
// fid 40..47 (W2) / 48..55 (W3), b = ks*2 + t2 (ks=0..3): feat-PERMUTED so the
// previous layer's C-regs [8*(ks&1)..+7] of tile (ks>>1) are the B-frag:
//   val = W[32t2 + (l&31)][32*(ks>>1) + 16*(ks&1) + 4*(l>>5) + 8*(i>>2) + (i&3)]
// ---------------------------------------------------------------------------
__global__ void prep_wfrag(const float* __restrict__ W1, const float* __restrict__ W2,
                           const float* __restrict__ W3, unsigned short* __restrict__ Wf) {
    int idx = blockIdx.x * blockDim.x + threadIdx.x;
    if (idx >= 56 * 64) return;
    int fid = idx >> 6, lane = idx & 63;
    int e31 = lane & 31, hi = lane >> 5;
    unsigned short* dstp = Wf + ((size_t)fid * 64 + lane) * 8;
    if (fid < 40) {
        int ks = fid >> 1, t = fid & 1;
        int n = 32 * t + e31;
        int k0 = 16 * ks + 8 * hi;
#pragma unroll
        for (int i = 0; i < 8; ++i) dstp[i] = f2bf(W1[n * 320 + k0 + i]);
    } else {
        const float* srcW = (fid < 48) ? W2 : W3;
        int b = (fid < 48) ? fid - 40 : fid - 48;
        int ks = b >> 1, t2 = b & 1;
        int n = 32 * t2 + e31;
        int cb = 32 * (ks >> 1) + 16 * (ks & 1) + 4 * hi;
#pragma unroll
        for (int i = 0; i < 8; ++i) dstp[i] = f2bf(srcW[n * 64 + cb + 8 * (i >> 2) + (i & 3)]);
    }
}

// ---------------------------------------------------------------------------
// node precompute: hVp = bf16 projx-scaled node rows, pj = ||projx(hV_n)||^2
// ---------------------------------------------------------------------------
__global__ void __launch_bounds__(256)
node_prep(const float* __restrict__ hV, const float* __restrict__ logc,
          unsigned short* __restrict__ hVp, float* __restrict__ pj, int n_nodes) {
    int wid  = (blockIdx.x * blockDim.x + threadIdx.x) >> 6;
    int lane = threadIdx.x & 63;
    if (wid >= n_nodes) return;
    float c    = __expf(logc[0]);
    float scq  = sqrtf(c);
    float maxn = (1.0f - 1e-5f) / scq;
    float x = hV[(size_t)wid * 64 + lane];
    float p = wred(x * x);
    float sS = fminf(maxn / fmaxf(sqrtf(p), EPSF), 1.0f);
    hVp[(size_t)wid * 64 + lane] = f2bf(x * sS);
    if (lane == 0) pj[wid] = sS * sS * p;
}

// ---------------------------------------------------------------------------
// CSR slot assignment: atomic histogram -> block scan -> slot fixup
// ---------------------------------------------------------------------------
__global__ void hist_kernel(const int* __restrict__ src, int* __restrict__ cnt,
                            int* __restrict__ slot, int n_edges) {
    int e = blockIdx.x * blockDim.x + threadIdx.x;
    if (e < n_edges) slot[e] = atomicAdd(&cnt[src[e]], 1);
}

__global__ void __launch_bounds__(1024)
scan_rowptr(const int* __restrict__ cnt, int* __restrict__ rowptr, int n) {
    __shared__ int wpart[16];
    int C   = (n + 1023) >> 10;
    int tid = threadIdx.x;
    int beg = tid * C;
    int end = beg + C; if (end > n) end = n;
    int s = 0;
    if (beg < n) for (int k = beg; k < end; ++k) s += cnt[k];
    int lane = tid & 63, wv = tid >> 6;
    int v = s;
#pragma unroll
    for (int off = 1; off < 64; off <<= 1) {
        int t = __shfl_up(v, off);
        if (lane >= off) v += t;
    }
    if (lane == 63) wpart[wv] = v;
    __syncthreads();
    if (tid < 64) {
        int t = (tid < 16) ? wpart[tid] : 0;
#pragma unroll
        for (int off = 1; off < 16; off <<= 1) {
            int u = __shfl_up(t, off);
            if (lane >= off) t += u;
        }
        if (tid < 16) wpart[tid] = t;
    }
    __syncthreads();
    int base = (wv ? wpart[wv - 1] : 0) + (v - s);
    if (beg < n) {
        int run = base;
        for (int k = beg; k < end; ++k) { rowptr[k] = run; run += cnt[k]; }
    }
    if (tid == 1023) rowptr[n] = wpart[15];
}

__global__ void slotfix_kernel(const int* __restrict__ src, const int* __restrict__ rowptr,
                               int* __restrict__ slot, int n_edges) {
    int e = blockIdx.x * blockDim.x + threadIdx.x;
    if (e < n_edges) slot[e] += rowptr[src[e]];
}

// ---------------------------------------------------------------------------
// transposed 32-edge mobius stage: v[2][16] (C layout: col=edge=lane&31,
// feat = 32t + (j&3) + 8*(j>>2) + 4*hi). Per-lane factors (edge pair on
// lanes l, l+32 -> single xor-32 reduce). B-frags = C-regs re-packed; weights
// carry the feat permutation. No LDS.
// ---------------------------------------------------------------------------
__device__ __forceinline__ void stage_mlp32(float (&v)[2][16],
                                            const bf16x8* __restrict__ Wfrag, int fbase,
                                            const float* __restrict__ bvec,
                                            float scq, float maxn, int lane, int hi) {
    float n2 = 0.f, rn2 = 0.f;
    float u[2][16];
#pragma unroll
    for (int t = 0; t < 2; ++t)
#pragma unroll
        for (int j = 0; j < 16; ++j) {
            float x = v[t][j];
            n2 = fmaf(x, x, n2);
            float y = fmaxf(x, 0.f);
            u[t][j] = y;
            rn2 = fmaf(y, y, rn2);
        }
    n2  += __shfl_xor(n2, 32);
    rn2 += __shfl_xor(rn2, 32);
    float n  = sqrtf(n2);
    float h  = fast_tanh_pos(scq * n) / (n * scq + EPSF);   // expmap0 factor
    float rn = h * sqrtf(rn2);
    float ps = fminf(maxn / fmaxf(rn, EPSF), 1.0f);
    float pn = rn * ps;
    float gg = fast_atanh01(fminf(scq * pn, 1.0f - 1e-5f)) / (scq * (pn + EPSF));
    float f2 = h * ps * gg;                                  // folded, post-applied

    f32x16 acc[2] = {};
#pragma unroll
    for (int ks = 0; ks < 4; ++ks) {
        int t = ks >> 1, jb = 8 * (ks & 1);
        union { bf16x8 b; unsigned w[4]; } B;
        B.w[0] = pkbf(u[t][jb + 0], u[t][jb + 1]);
        B.w[1] = pkbf(u[t][jb + 2], u[t][jb + 3]);
        B.w[2] = pkbf(u[t][jb + 4], u[t][jb + 5]);
        B.w[3] = pkbf(u[t][jb + 6], u[t][jb + 7]);
#pragma unroll
        for (int t2 = 0; t2 < 2; ++t2)
            acc[t2] = __builtin_amdgcn_mfma_f32_32x32x16_bf16(
                Wfrag[(size_t)(fbase + ks * 2 + t2) * 64 + lane], B.b, acc[t2], 0, 0, 0);
    }
#pragma unroll
    for (int t2 = 0; t2 < 2; ++t2)
#pragma unroll
        for (int q = 0; q < 4; ++q) {
            const float4 bv = *reinterpret_cast<const float4*>(&bvec[32 * t2 + 8 * q + 4 * hi]);
            v[t2][4 * q + 0] = fmaf(f2, acc[t2][4 * q + 0], bv.x);
            v[t2][4 * q + 1] = fmaf(f2, acc[t2][4 * q + 1], bv.y);
            v[t2][4 * q + 2] = fmaf(f2, acc[t2][4 * q + 2], bv.z);
            v[t2][4 * q + 3] = fmaf(f2, acc[t2][4 * q + 3], bv.w);
        }
}

// ---------------------------------------------------------------------------
// edge kernel: wave = 32 edges (edge = lane&31, hi = lane>>5 = k-half).
// ---------------------------------------------------------------------------
__global__ void __launch_bounds__(256)
edge_mfma(const float* __restrict__ hE, const int* __restrict__ src,
          const int* __restrict__ dst, const float* __restrict__ logc,
          const unsigned short* __restrict__ Wf, const unsigned short* __restrict__ hVp,
          const float* __restrict__ pj,
          const float* __restrict__ b1, const float* __restrict__ b2,
          const float* __restrict__ b3, const int* __restrict__ slot,
          unsigned short* __restrict__ tg, int n_edges) {
    int lane = threadIdx.x & 63;
    int w    = threadIdx.x >> 6;
    int tile = blockIdx.x * 4 + w;
    int e0 = tile * 32;
    if (e0 >= n_edges) return;

    float c    = __expf(logc[0]);
    float scq  = sqrtf(c);
    float maxn = (1.0f - 1e-5f) / scq;

    int e31 = lane & 31, hi = lane >> 5;
    int ev = e0 + e31; if (ev >= n_edges) ev = n_edges - 1;
    int s16 = src[ev], d16 = dst[ev];
    float pjS = pj[s16], pjD = pj[d16];

    const bf16x8* Wfrag = reinterpret_cast<const bf16x8*>(Wf);

    // node fragments: lane (e,hi) takes 8 bf16 at offset 16q + 8hi, q=0..3
    const bf16x8* vsp = reinterpret_cast<const bf16x8*>(hVp + (size_t)s16 * 64);
    const bf16x8* vdp = reinterpret_cast<const bf16x8*>(hVp + (size_t)d16 * 64);
    bf16x8 aS[4], aD[4];
#pragma unroll
    for (int q = 0; q < 4; ++q) { aS[q] = vsp[2 * q + hi]; aD[q] = vdp[2 * q + hi]; }

    // GEMM1: hE streamed per k-step (load -> square -> cvt -> 2 MFMA)
    f32x16 accE[2] = {}, accV[2] = {};
    float pE = 0.f;
    const float* eb = hE + (size_t)ev * 192 + 8 * hi;
#pragma unroll
    for (int ks = 0; ks < 12; ++ks) {
        const float4* p4 = reinterpret_cast<const float4*>(eb + 16 * ks);
        float4 a0 = p4[0], a1 = p4[1];
        pE += a0.x*a0.x + a0.y*a0.y + a0.z*a0.z + a0.w*a0.w
            + a1.x*a1.x + a1.y*a1.y + a1.z*a1.z + a1.w*a1.w;
        union { bf16x8 b; unsigned u[4]; } cv;
        cv.u[0] = pkbf(a0.x, a0.y);
        cv.u[1] = pkbf(a0.z, a0.w);
        cv.u[2] = pkbf(a1.x, a1.y);
        cv.u[3] = pkbf(a1.z, a1.w);
#pragma unroll
        for (int t = 0; t < 2; ++t)
            accE[t] = __builtin_amdgcn_mfma_f32_32x32x16_bf16(
                Wfrag[(size_t)(ks * 2 + t) * 64 + lane], cv.b, accE[t], 0, 0, 0);
    }
#pragma unroll
    for (int q = 0; q < 4; ++q) {
#pragma unroll
        for (int t = 0; t < 2; ++t)
            accV[t] = __builtin_amdgcn_mfma_f32_32x32x16_bf16(
                Wfrag[(size_t)((12 + q) * 2 + t) * 64 + lane], aS[q], accV[t], 0, 0, 0);
    }
#pragma unroll
    for (int q = 0; q < 4; ++q) {
#pragma unroll
        for (int t = 0; t < 2; ++t)
            accV[t] = __builtin_amdgcn_mfma_f32_32x32x16_bf16(
                Wfrag[(size_t)((16 + q) * 2 + t) * 64 + lane], aD[q], accV[t], 0, 0, 0);
    }

    pE += __shfl_xor(pE, 32);
    float sE = fminf(maxn / fmaxf(sqrtf(pE), EPSF), 1.0f);
    float nt = sqrtf(sE * sE * pE + pjS + pjD);
    float gq = fast_atanh01(fminf(scq * nt, 1.0f - 1e-5f)) / (scq * (nt + EPSF));

    // epilogue 1: v = gq*(sE*accE + accV) + b1   (per-lane scalars)
    float v[2][16];
#pragma unroll
    for (int t = 0; t < 2; ++t)
#pragma unroll
        for (int q = 0; q < 4; ++q) {
            const float4 bv = *reinterpret_cast<const float4*>(&b1[32 * t + 8 * q + 4 * hi]);
            v[t][4*q+0] = fmaf(gq, fmaf(sE, accE[t][4*q+0], accV[t][4*q+0]), bv.x);
            v[t][4*q+1] = fmaf(gq, fmaf(sE, accE[t][4*q+1], accV[t][4*q+1]), bv.y);
            v[t][4*q+2] = fmaf(gq, fmaf(sE, accE[t][4*q+2], accV[t][4*q+2]), bv.z);
            v[t][4*q+3] = fmaf(gq, fmaf(sE, accE[t][4*q+3], accV[t][4*q+3]), bv.w);
        }

    stage_mlp32(v, Wfrag, 40, b2, scq, maxn, lane, hi);
    stage_mlp32(v, Wfrag, 48, b3, scq, maxn, lane, hi);

    // tangent = logmap0(expmap0(v3)): per-lane factor, direct register store
    float n2 = 0.f;
#pragma unroll
    for (int t = 0; t < 2; ++t)
#pragma unroll
        for (int j = 0; j < 16; ++j) n2 = fmaf(v[t][j], v[t][j], n2);
    n2 += __shfl_xor(n2, 32);
    float n  = sqrtf(n2);
    float h  = fast_tanh_pos(scq * n) / (n * scq + EPSF);
    float hn = h * n;
    float g4 = fast_atanh01(fminf(scq * hn, 1.0f - 1e-5f)) / (scq * (hn + EPSF));
    float fT = g4 * h;

    if (e0 + e31 < n_edges) {
        int sl = slot[ev];
        unsigned short* orow = tg + (size_t)sl * 64;
#pragma unroll
        for (int t = 0; t < 2; ++t)
#pragma unroll
            for (int q = 0; q < 4; ++q) {
                uint2 o;
                o.x = pkbf(fT * v[t][4*q+0], fT * v[t][4*q+1]);
                o.y = pkbf(fT * v[t][4*q+2], fT * v[t][4*q+3]);
                *reinterpret_cast<uint2*>(&orow[32 * t + 8 * q + 4 * hi]) = o;
            }
    }
}

// ---------------------------------------------------------------------------
// node kernel: contiguous CSR range, 4 edges/iter (uint2 loads), then
// expmap0 -> mobius_add -> projx with wave reductions.
// ---------------------------------------------------------------------------
__global__ void __launch_bounds__(256)
node_gather(const float* __restrict__ hV, const float* __restrict__ logc,
            const unsigned short* __restrict__ tg, const int* __restrict__ rowptr,
            float* __restrict__ out, int n_nodes) {
    int wid  = (blockIdx.x * blockDim.x + threadIdx.x) >> 6;
    int lane = threadIdx.x & 63;
    if (wid >= n_nodes) return;

    float c    = __expf(logc[0]);
    float scq  = sqrtf(c);
    float maxn = (1.0f - 1e-5f) / scq;

    int beg = rowptr[wid], end = rowptr[wid + 1];
    int g = lane >> 4, i15 = lane & 15;
    float s0 = 0.f, s1 = 0.f, s2 = 0.f, s3 = 0.f;
    for (int i = beg + g; i < end; i += 4) {
        uint2 p = *reinterpret_cast<const uint2*>(&tg[(size_t)i * 64 + i15 * 4]);
        s0 += bf2f((unsigned short)(p.x & 0xffff));
        s1 += bf2f((unsigned short)(p.x >> 16));
        s2 += bf2f((unsigned short)(p.y & 0xffff));
        s3 += bf2f((unsigned short)(p.y >> 16));
    }
    s0 += __shfl_xor(s0, 16); s0 += __shfl_xor(s0, 32);
    s1 += __shfl_xor(s1, 16); s1 += __shfl_xor(s1, 32);
    s2 += __shfl_xor(s2, 16); s2 += __shfl_xor(s2, 32);
    s3 += __shfl_xor(s3, 16); s3 += __shfl_xor(s3, 32);
    int srcl = lane >> 2;
    float a0 = __shfl(s0, srcl), a1 = __shfl(s1, srcl);
    float a2 = __shfl(s2, srcl), a3 = __shfl(s3, srcl);
    float ssum = (lane & 2) ? ((lane & 1) ? a3 : a2) : ((lane & 1) ? a1 : a0);

    float inv = 1.f / fmaxf((float)(end - beg), 1.f);
    float at  = ssum * inv;

    float an2 = wred(at * at);
    float an  = sqrtf(an2);
    float ae  = fast_tanh_pos(scq * an) / (an * scq + EPSF);

    float xv  = hV[(size_t)wid * 64 + lane];
    float hs2 = wred(xv * xv);
    float sX  = fminf(maxn / fmaxf(sqrtf(hs2), EPSF), 1.0f);

    float x = sX * xv, y = ae * at;
    float x2 = wred(x * x);
    float y2 = wred(y * y);
    float xy = wred(x * y);

    float ca = 1.f + 2.f * c * xy + c * y2;
    float cb = 1.f - c * x2;
    float id = 1.f / (1.f + 2.f * c * xy + c * c * x2 * y2 + EPSF);

    float r   = (ca * x + cb * y) * id;
    float rn2 = wred(r * r);
    float rs  = fminf(maxn / fmaxf(sqrtf(rn2), EPSF), 1.0f);

    out[(size_t)wid * 64 + lane] = rs * r;
}

// ---------------------------------------------------------------------------
extern "C" void kernel_launch(void* const* d_in, const int* in_sizes, int n_in,
                              void* d_out, int out_size, void* d_ws, size_t ws_size,
                              hipStream_t stream) {
    const float* hV   = (const float*)d_in[0];
    const float* hE   = (const float*)d_in[1];
    const int*   src  = (const int*)d_in[2];
    const int*   dst  = (const int*)d_in[3];
    const float* logc = (const float*)d_in[4];
    const float* W1   = (const float*)d_in[5];
    const float* b1   = (const float*)d_in[6];
    const float* W2   = (const float*)d_in[7];
    const float* b2   = (const float*)d_in[8];
    const float* W3   = (const float*)d_in[9];
    const float* b3   = (const float*)d_in[10];

    int n_nodes = in_sizes[0] / 64;
    int n_edges = in_sizes[2];
    float* out = (float*)d_out;

    char* wsb = (char*)d_ws;
    unsigned short* Wf = (unsigned short*)wsb;                 // 56*512 ushort
    size_t off = 56 * 512 * sizeof(unsigned short);
    int* cnt    = (int*)(wsb + off);   off += (size_t)n_nodes * 4;
    int* rowptr = (int*)(wsb + off);   off += (size_t)(n_nodes + 1) * 4;
    int* slot   = (int*)(wsb + off);   off += (size_t)n_edges * 4;
    float* pj   = (float*)(wsb + off); off += (size_t)n_nodes * 4;
    off = (off + 15) & ~(size_t)15;
    unsigned short* hVp = (unsigned short*)(wsb + off);        // N*64 bf16
    off += (size_t)n_nodes * 64 * 2;
    off = (off + 15) & ~(size_t)15;
    unsigned short* tg = (unsigned short*)(wsb + off);         // E*64 bf16

    hipMemsetAsync(cnt, 0, (size_t)n_nodes * sizeof(int), stream);

    prep_wfrag<<<(56 * 64 + 255) / 256, 256, 0, stream>>>(W1, W2, W3, Wf);
    node_prep<<<(n_nodes + 3) / 4, 256, 0, stream>>>(hV, logc, hVp, pj, n_nodes);
    hist_kernel<<<(n_edges + 255) / 256, 256, 0, stream>>>(src, cnt, slot, n_edges);
    scan_rowptr<<<1, 1024, 0, stream>>>(cnt, rowptr, n_nodes);
    slotfix_kernel<<<(n_edges + 255) / 256, 256, 0, stream>>>(src, rowptr, slot, n_edges);

    int tiles = (n_edges + 31) / 32;
    edge_mfma<<<(tiles + 3) / 4, 256, 0, stream>>>(
        hE, src, dst, logc, Wf, hVp, pj, b1, b2, b3, slot, tg, n_edges);

    node_gather<<<(n_nodes + 3) / 4, 256, 0, stream>>>(
        hV, logc, tg, rowptr, out, n_nodes);
}

// Round 8
// 220.889 us; speedup vs baseline: 1.0969x; 1.0969x over previous
//
#include <hip/hip_runtime.h>
#include <hip/hip_bf16.h>
#include <math.h>

#define EPSF 1e-15f

typedef __attribute__((ext_vector_type(8))) short bf16x8;
typedef __attribute__((ext_vector_type(16))) float f32x16;

__device__ __forceinline__ unsigned short f2bf(float x) {
    unsigned u = __float_as_uint(x);
    u += 0x7fffu + ((u >> 16) & 1u);
    return (unsigned short)(u >> 16);
}
__device__ __forceinline__ float bf2f(unsigned short b) {
    return __uint_as_float(((unsigned)b) << 16);
}
__device__ __forceinline__ unsigned pkbf(float lo, float hi) {
    __hip_bfloat162 h = __float22bfloat162_rn(make_float2(lo, hi));
    return *reinterpret_cast<unsigned*>(&h);
}
// tanh(x) for x>=0; identity form + small-x polynomial
__device__ __forceinline__ float fast_tanh_pos(float x) {
    if (x < 0.25f) { float x2 = x * x; return x * (1.0f - x2 * (0.33333334f - 0.13333334f * x2)); }
    float e = __expf(2.0f * x);
    return 1.0f - 2.0f / (e + 1.0f);
}
// atanh(y) for 0<=y<=1-1e-5
__device__ __forceinline__ float fast_atanh01(float y) {
    if (y < 0.125f) { float y2 = y * y; return y * (1.0f + y2 * (0.33333334f + 0.2f * y2)); }
    return 0.5f * __logf((1.0f + y) / (1.0f - y));
}

__device__ __forceinline__ float wred(float v) {
#pragma unroll
    for (int off = 32; off; off >>= 1) v += __shfl_xor(v, off);
    return v;
}

// ---------------------------------------------------------------------------
// prep: weight fragments for mfma_f32_32x32x16_bf16 (A-operand = weights).
// Layouts unchanged from R7 (verified by absmax).
// ---------------------------------------------------------------------------
__global__ void prep_wfrag(const float* __restrict__ W1, const float* __restrict__ W2,
                           const float* __restrict__ W3, unsigned short* __restrict__ Wf) {
    int idx = blockIdx.x * blockDim.x + threadIdx.x;
    if (idx >= 56 * 64) return;
    int fid = idx >> 6, lane = idx & 63;
    int e31 = lane & 31, hi = lane >> 5;
    unsigned short* dstp = Wf + ((size_t)fid * 64 + lane) * 8;
    if (fid < 40) {
        int ks = fid >> 1, t = fid & 1;
        int n = 32 * t + e31;
        int k0 = 16 * ks + 8 * hi;
#pragma unroll
        for (int i = 0; i < 8; ++i) dstp[i] = f2bf(W1[n * 320 + k0 + i]);
    } else {
        const float* srcW = (fid < 48) ? W2 : W3;
        int b = (fid < 48) ? fid - 40 : fid - 48;
        int ks = b >> 1, t2 = b & 1;
        int n = 32 * t2 + e31;
        int cb = 32 * (ks >> 1) + 16 * (ks & 1) + 4 * hi;
#pragma unroll
        for (int i = 0; i < 8; ++i) dstp[i] = f2bf(srcW[n * 64 + cb + 8 * (i >> 2) + (i & 3)]);
    }
}

// ---------------------------------------------------------------------------
// node precompute: hVp = bf16 projx-scaled node rows, pj = ||projx(hV_n)||^2
// ---------------------------------------------------------------------------
__global__ void __launch_bounds__(256)
node_prep(const float* __restrict__ hV, const float* __restrict__ logc,
          unsigned short* __restrict__ hVp, float* __restrict__ pj, int n_nodes) {
    int wid  = (blockIdx.x * blockDim.x + threadIdx.x) >> 6;
    int lane = threadIdx.x & 63;
    if (wid >= n_nodes) return;
    float c    = __expf(logc[0]);
    float scq  = sqrtf(c);
    float maxn = (1.0f - 1e-5f) / scq;
    float x = hV[(size_t)wid * 64 + lane];
    float p = wred(x * x);
    float sS = fminf(maxn / fmaxf(sqrtf(p), EPSF), 1.0f);
    hVp[(size_t)wid * 64 + lane] = f2bf(x * sS);
    if (lane == 0) pj[wid] = sS * sS * p;
}

// ---------------------------------------------------------------------------
// CSR slot assignment: atomic histogram -> block scan -> slot fixup
// ---------------------------------------------------------------------------
__global__ void hist_kernel(const int* __restrict__ src, int* __restrict__ cnt,
                            int* __restrict__ slot, int n_edges) {
    int e = blockIdx.x * blockDim.x + threadIdx.x;
    if (e < n_edges) slot[e] = atomicAdd(&cnt[src[e]], 1);
}

__global__ void __launch_bounds__(1024)
scan_rowptr(const int* __restrict__ cnt, int* __restrict__ rowptr, int n) {
    __shared__ int wpart[16];
    int C   = (n + 1023) >> 10;
    int tid = threadIdx.x;
    int beg = tid * C;
    int end = beg + C; if (end > n) end = n;
    int s = 0;
    if (beg < n) for (int k = beg; k < end; ++k) s += cnt[k];
    int lane = tid & 63, wv = tid >> 6;
    int v = s;
#pragma unroll
    for (int off = 1; off < 64; off <<= 1) {
        int t = __shfl_up(v, off);
        if (lane >= off) v += t;
    }
    if (lane == 63) wpart[wv] = v;
    __syncthreads();
    if (tid < 64) {
        int t = (tid < 16) ? wpart[tid] : 0;
#pragma unroll
        for (int off = 1; off < 16; off <<= 1) {
            int u = __shfl_up(t, off);
            if (lane >= off) t += u;
        }
        if (tid < 16) wpart[tid] = t;
    }
    __syncthreads();
    int base = (wv ? wpart[wv - 1] : 0) + (v - s);
    if (beg < n) {
        int run = base;
        for (int k = beg; k < end; ++k) { rowptr[k] = run; run += cnt[k]; }
    }
    if (tid == 1023) rowptr[n] = wpart[15];
}

__global__ void slotfix_kernel(const int* __restrict__ src, const int* __restrict__ rowptr,
                               int* __restrict__ slot, int n_edges) {
    int e = blockIdx.x * blockDim.x + threadIdx.x;
    if (e < n_edges) slot[e] += rowptr[src[e]];
}

// ---------------------------------------------------------------------------
// transposed 32-edge mobius stage (R7-verified math), Wf frags read from LDS.
// ---------------------------------------------------------------------------
__device__ __forceinline__ void stage_mlp32(float (&v)[2][16],
                                            const unsigned short* WfL, int fbase,
                                            const float* __restrict__ bvec,
                                            float scq, float maxn, int lane, int hi) {
    float n2 = 0.f, rn2 = 0.f;
    float u[2][16];
#pragma unroll
    for (int t = 0; t < 2; ++t)
#pragma unroll
        for (int j = 0; j < 16; ++j) {
            float x = v[t][j];
            n2 = fmaf(x, x, n2);
            float y = fmaxf(x, 0.f);
            u[t][j] = y;
            rn2 = fmaf(y, y, rn2);
        }
    n2  += __shfl_xor(n2, 32);
    rn2 += __shfl_xor(rn2, 32);
    float n  = sqrtf(n2);
    float h  = fast_tanh_pos(scq * n) / (n * scq + EPSF);   // expmap0 factor
    float rn = h * sqrtf(rn2);
    float ps = fminf(maxn / fmaxf(rn, EPSF), 1.0f);
    float pn = rn * ps;
    float gg = fast_atanh01(fminf(scq * pn, 1.0f - 1e-5f)) / (scq * (pn + EPSF));
    float f2 = h * ps * gg;                                  // folded, post-applied

    f32x16 acc[2] = {};
#pragma unroll
    for (int ks = 0; ks < 4; ++ks) {
        int t = ks >> 1, jb = 8 * (ks & 1);
        union { bf16x8 b; unsigned w[4]; } B;
        B.w[0] = pkbf(u[t][jb + 0], u[t][jb + 1]);
        B.w[1] = pkbf(u[t][jb + 2], u[t][jb + 3]);
        B.w[2] = pkbf(u[t][jb + 4], u[t][jb + 5]);
        B.w[3] = pkbf(u[t][jb + 6], u[t][jb + 7]);
#pragma unroll
        for (int t2 = 0; t2 < 2; ++t2) {
            bf16x8 wf = *reinterpret_cast<const bf16x8*>(
                &WfL[((fbase + ks * 2 + t2) * 64 + lane) * 8]);
            acc[t2] = __builtin_amdgcn_mfma_f32_32x32x16_bf16(wf, B.b, acc[t2], 0, 0, 0);
        }
    }
#pragma unroll
    for (int t2 = 0; t2 < 2; ++t2)
#pragma unroll
        for (int q = 0; q < 4; ++q) {
            const float4 bv = *reinterpret_cast<const float4*>(&bvec[32 * t2 + 8 * q + 4 * hi]);
            v[t2][4 * q + 0] = fmaf(f2, acc[t2][4 * q + 0], bv.x);
            v[t2][4 * q + 1] = fmaf(f2, acc[t2][4 * q + 1], bv.y);
            v[t2][4 * q + 2] = fmaf(f2, acc[t2][4 * q + 2], bv.z);
            v[t2][4 * q + 3] = fmaf(f2, acc[t2][4 * q + 3], bv.w);
        }
}

// ---------------------------------------------------------------------------
// edge kernel: wave = 32 edges. Wf staged in LDS (shared by 4 waves);
// all 24 hE loads issued up front (latency batched under one waitcnt).
// ---------------------------------------------------------------------------
__global__ void __launch_bounds__(256, 2)
edge_mfma(const float* __restrict__ hE, const int* __restrict__ src,
          const int* __restrict__ dst, const float* __restrict__ logc,
          const unsigned short* __restrict__ Wf, const unsigned short* __restrict__ hVp,
          const float* __restrict__ pj,
          const float* __restrict__ b1, const float* __restrict__ b2,
          const float* __restrict__ b3, const int* __restrict__ slot,
          unsigned short* __restrict__ tg, int n_edges) {
    __shared__ __align__(16) unsigned short WfL[28672];   // 56 frags * 512 ushort = 57344 B
    {
        const uint4* wsrc = reinterpret_cast<const uint4*>(Wf);
        uint4* wdst = reinterpret_cast<uint4*>(WfL);
#pragma unroll
        for (int i = 0; i < 14; ++i)
            wdst[i * 256 + threadIdx.x] = wsrc[i * 256 + threadIdx.x];
    }
    __syncthreads();   // before any early-return: all waves participate

    int lane = threadIdx.x & 63;
    int w    = threadIdx.x >> 6;
    int tile = blockIdx.x * 4 + w;
    int e0 = tile * 32;
    if (e0 >= n_edges) return;

    float c    = __expf(logc[0]);
    float scq  = sqrtf(c);
    float maxn = (1.0f - 1e-5f) / scq;

    int e31 = lane & 31, hi = lane >> 5;
    int ev = e0 + e31; if (ev >= n_edges) ev = n_edges - 1;
    int s16 = src[ev], d16 = dst[ev];
    float pjS = pj[s16], pjD = pj[d16];
    int sl = slot[ev];

    // ---- issue ALL hE loads up front (24 float4, static regs) ----
    float4 ha[24];
    const float* eb = hE + (size_t)ev * 192 + 8 * hi;
#pragma unroll
    for (int ks = 0; ks < 12; ++ks) {
        const float4* p4 = reinterpret_cast<const float4*>(eb + 16 * ks);
        ha[2 * ks]     = p4[0];
        ha[2 * ks + 1] = p4[1];
    }
    // ---- node fragments (8 loads, issued before MFMA chain) ----
    const bf16x8* vsp = reinterpret_cast<const bf16x8*>(hVp + (size_t)s16 * 64);
    const bf16x8* vdp = reinterpret_cast<const bf16x8*>(hVp + (size_t)d16 * 64);
    bf16x8 aS[4], aD[4];
#pragma unroll
    for (int q = 0; q < 4; ++q) { aS[q] = vsp[2 * q + hi]; aD[q] = vdp[2 * q + hi]; }

    // ---- GEMM1: consume hE batch (squares -> cvt -> LDS Wf -> MFMA) ----
    f32x16 accE[2] = {}, accV[2] = {};
    float pE = 0.f;
#pragma unroll
    for (int ks = 0; ks < 12; ++ks) {
        float4 a0 = ha[2 * ks], a1 = ha[2 * ks + 1];
        pE += a0.x*a0.x + a0.y*a0.y + a0.z*a0.z + a0.w*a0.w
            + a1.x*a1.x + a1.y*a1.y + a1.z*a1.z + a1.w*a1.w;
        union { bf16x8 b; unsigned u[4]; } cv;
        cv.u[0] = pkbf(a0.x, a0.y);
        cv.u[1] = pkbf(a0.z, a0.w);
        cv.u[2] = pkbf(a1.x, a1.y);
        cv.u[3] = pkbf(a1.z, a1.w);
#pragma unroll
        for (int t = 0; t < 2; ++t) {
            bf16x8 wf = *reinterpret_cast<const bf16x8*>(&WfL[((ks * 2 + t) * 64 + lane) * 8]);
            accE[t] = __builtin_amdgcn_mfma_f32_32x32x16_bf16(wf, cv.b, accE[t], 0, 0, 0);
        }
    }
#pragma unroll
    for (int q = 0; q < 4; ++q) {
#pragma unroll
        for (int t = 0; t < 2; ++t) {
            bf16x8 wf = *reinterpret_cast<const bf16x8*>(&WfL[(((12 + q) * 2 + t) * 64 + lane) * 8]);
            accV[t] = __builtin_amdgcn_mfma_f32_32x32x16_bf16(wf, aS[q], accV[t], 0, 0, 0);
        }
    }
#pragma unroll
    for (int q = 0; q < 4; ++q) {
#pragma unroll
        for (int t = 0; t < 2; ++t) {
            bf16x8 wf = *reinterpret_cast<const bf16x8*>(&WfL[(((16 + q) * 2 + t) * 64 + lane) * 8]);
            accV[t] = __builtin_amdgcn_mfma_f32_32x32x16_bf16(wf, aD[q], accV[t], 0, 0, 0);
        }
    }

    pE += __shfl_xor(pE, 32);
    float sE = fminf(maxn / fmaxf(sqrtf(pE), EPSF), 1.0f);
    float nt = sqrtf(sE * sE * pE + pjS + pjD);
    float gq = fast_atanh01(fminf(scq * nt, 1.0f - 1e-5f)) / (scq * (nt + EPSF));

    // epilogue 1: v = gq*(sE*accE + accV) + b1   (per-lane scalars)
    float v[2][16];
#pragma unroll
    for (int t = 0; t < 2; ++t)
#pragma unroll
        for (int q = 0; q < 4; ++q) {
            const float4 bv = *reinterpret_cast<const float4*>(&b1[32 * t + 8 * q + 4 * hi]);
            v[t][4*q+0] = fmaf(gq, fmaf(sE, accE[t][4*q+0], accV[t][4*q+0]), bv.x);
            v[t][4*q+1] = fmaf(gq, fmaf(sE, accE[t][4*q+1], accV[t][4*q+1]), bv.y);
            v[t][4*q+2] = fmaf(gq, fmaf(sE, accE[t][4*q+2], accV[t][4*q+2]), bv.z);
            v[t][4*q+3] = fmaf(gq, fmaf(sE, accE[t][4*q+3], accV[t][4*q+3]), bv.w);
        }

    stage_mlp32(v, WfL, 40, b2, scq, maxn, lane, hi);
    stage_mlp32(v, WfL, 48, b3, scq, maxn, lane, hi);

    // tangent = logmap0(expmap0(v3)): per-lane factor, direct register store
    float n2 = 0.f;
#pragma unroll
    for (int t = 0; t < 2; ++t)
#pragma unroll
        for (int j = 0; j < 16; ++j) n2 = fmaf(v[t][j], v[t][j], n2);
    n2 += __shfl_xor(n2, 32);
    float n  = sqrtf(n2);
    float h  = fast_tanh_pos(scq * n) / (n * scq + EPSF);
    float hn = h * n;
    float g4 = fast_atanh01(fminf(scq * hn, 1.0f - 1e-5f)) / (scq * (hn + EPSF));
    float fT = g4 * h;

    if (e0 + e31 < n_edges) {
        unsigned short* orow = tg + (size_t)sl * 64;
#pragma unroll
        for (int t = 0; t < 2; ++t)
#pragma unroll
            for (int q = 0; q < 4; ++q) {
                uint2 o;
                o.x = pkbf(fT * v[t][4*q+0], fT * v[t][4*q+1]);
                o.y = pkbf(fT * v[t][4*q+2], fT * v[t][4*q+3]);
                *reinterpret_cast<uint2*>(&orow[32 * t + 8 * q + 4 * hi]) = o;
            }
    }
}

// ---------------------------------------------------------------------------
// node kernel: contiguous CSR range, 4 edges/iter (uint2 loads), then
// expmap0 -> mobius_add -> projx with wave reductions.
// ---------------------------------------------------------------------------
__global__ void __launch_bounds__(256)
node_gather(const float* __restrict__ hV, const float* __restrict__ logc,
            const unsigned short* __restrict__ tg, const int* __restrict__ rowptr,
            float* __restrict__ out, int n_nodes) {
    int wid  = (blockIdx.x * blockDim.x + threadIdx.x) >> 6;
    int lane = threadIdx.x & 63;
    if (wid >= n_nodes) return;

    float c    = __expf(logc[0]);
    float scq  = sqrtf(c);
    float maxn = (1.0f - 1e-5f) / scq;

    int beg = rowptr[wid], end = rowptr[wid + 1];
    int g = lane >> 4, i15 = lane & 15;
    float s0 = 0.f, s1 = 0.f, s2 = 0.f, s3 = 0.f;
    for (int i = beg + g; i < end; i += 4) {
        uint2 p = *reinterpret_cast<const uint2*>(&tg[(size_t)i * 64 + i15 * 4]);
        s0 += bf2f((unsigned short)(p.x & 0xffff));
        s1 += bf2f((unsigned short)(p.x >> 16));
        s2 += bf2f((unsigned short)(p.y & 0xffff));
        s3 += bf2f((unsigned short)(p.y >> 16));
    }
    s0 += __shfl_xor(s0, 16); s0 += __shfl_xor(s0, 32);
    s1 += __shfl_xor(s1, 16); s1 += __shfl_xor(s1, 32);
    s2 += __shfl_xor(s2, 16); s2 += __shfl_xor(s2, 32);
    s3 += __shfl_xor(s3, 16); s3 += __shfl_xor(s3, 32);
    int srcl = lane >> 2;
    float a0 = __shfl(s0, srcl), a1 = __shfl(s1, srcl);
    float a2 = __shfl(s2, srcl), a3 = __shfl(s3, srcl);
    float ssum = (lane & 2) ? ((lane & 1) ? a3 : a2) : ((lane & 1) ? a1 : a0);

    float inv = 1.f / fmaxf((float)(end - beg), 1.f);
    float at  = ssum * inv;

    float an2 = wred(at * at);
    float an  = sqrtf(an2);
    float ae  = fast_tanh_pos(scq * an) / (an * scq + EPSF);

    float xv  = hV[(size_t)wid * 64 + lane];
    float hs2 = wred(xv * xv);
    float sX  = fminf(maxn / fmaxf(sqrtf(hs2), EPSF), 1.0f);

    float x = sX * xv, y = ae * at;
    float x2 = wred(x * x);
    float y2 = wred(y * y);
    float xy = wred(x * y);

    float ca = 1.f + 2.f * c * xy + c * y2;
    float cb = 1.f - c * x2;
    float id = 1.f / (1.f + 2.f * c * xy + c * c * x2 * y2 + EPSF);

    float r   = (ca * x + cb * y) * id;
    float rn2 = wred(r * r);
    float rs  = fminf(maxn / fmaxf(sqrtf(rn2), EPSF), 1.0f);

    out[(size_t)wid * 64 + lane] = rs * r;
}

// ---------------------------------------------------------------------------
extern "C" void kernel_launch(void* const* d_in, const int* in_sizes, int n_in,
                              void* d_out, int out_size, void* d_ws, size_t ws_size,
                              hipStream_t stream) {
    const float* hV   = (const float*)d_in[0];
    const float* hE   = (const float*)d_in[1];
    const int*   src  = (const int*)d_in[2];
    const int*   dst  = (const int*)d_in[3];
    const float* logc = (const float*)d_in[4];
    const float* W1   = (const float*)d_in[5];
    const float* b1   = (const float*)d_in[6];
    const float* W2   = (const float*)d_in[7];
    const float* b2   = (const float*)d_in[8];
    const float* W3   = (const float*)d_in[9];
    const float* b3   = (const float*)d_in[10];

    int n_nodes = in_sizes[0] / 64;
    int n_edges = in_sizes[2];
    float* out = (float*)d_out;

    char* wsb = (char*)d_ws;
    unsigned short* Wf = (unsigned short*)wsb;                 // 56*512 ushort
    size_t off = 56 * 512 * sizeof(unsigned short);
    int* cnt    = (int*)(wsb + off);   off += (size_t)n_nodes * 4;
    int* rowptr = (int*)(wsb + off);   off += (size_t)(n_nodes + 1) * 4;
    int* slot   = (int*)(wsb + off);   off += (size_t)n_edges * 4;
    float* pj   = (float*)(wsb + off); off += (size_t)n_nodes * 4;
    off = (off + 15) & ~(size_t)15;
    unsigned short* hVp = (unsigned short*)(wsb + off);        // N*64 bf16
    off += (size_t)n_nodes * 64 * 2;
    off = (off + 15) & ~(size_t)15;
    unsigned short* tg = (unsigned short*)(wsb + off);         // E*64 bf16

    hipMemsetAsync(cnt, 0, (size_t)n_nodes * sizeof(int), stream);

    prep_wfrag<<<(56 * 64 + 255) / 256, 256, 0, stream>>>(W1, W2, W3, Wf);
    node_prep<<<(n_nodes + 3) / 4, 256, 0, stream>>>(hV, logc, hVp, pj, n_nodes);
    hist_kernel<<<(n_edges + 255) / 256, 256, 0, stream>>>(src, cnt, slot, n_edges);
    scan_rowptr<<<1, 1024, 0, stream>>>(cnt, rowptr, n_nodes);
    slotfix_kernel<<<(n_edges + 255) / 256, 256, 0, stream>>>(src, rowptr, slot, n_edges);

    int tiles = (n_edges + 31) / 32;
    edge_mfma<<<(tiles + 3) / 4, 256, 0, stream>>>(
        hE, src, dst, logc, Wf, hVp, pj, b1, b2, b3, slot, tg, n_edges);

    node_gather<<<(n_nodes + 3) / 4, 256, 0, stream>>>(
        hV, logc, tg, rowptr, out, n_nodes);
}